// Round 1
// 6734.206 us; speedup vs baseline: 1.9073x; 1.9073x over previous
//
#include <hip/hip_runtime.h>
#include <math.h>

#define Bsz 4
#define Sseq 1024
#define Dm 1024
#define Hh 16
#define DHd 64
#define Ll 4
#define Vv 32000
#define NT (Bsz*Sseq)   /* 4096 tokens */
#define Dff 4096

typedef short short8 __attribute__((ext_vector_type(8)));
typedef float f32x4 __attribute__((ext_vector_type(4)));
typedef unsigned short ushort8v __attribute__((ext_vector_type(8)));

// ---------------- state encoder + positional embeddings ----------------
__global__ __launch_bounds__(256) void encoder_kernel(
    const float* __restrict__ states, const int* __restrict__ timesteps,
    const float* __restrict__ w1, const float* __restrict__ b1,
    const float* __restrict__ w2, const float* __restrict__ b2,
    const float* __restrict__ w3, const float* __restrict__ b3,
    const float* __restrict__ pos_emb, const float* __restrict__ gpe,
    float* __restrict__ x)
{
  int bs = blockIdx.x;
  int b = bs / Sseq, s = bs % Sseq;
  int tid = threadIdx.x;
  __shared__ float st[4], h1[16], h2[16];
  if (tid < 4) st[tid] = states[bs*4 + tid];
  __syncthreads();
  if (tid < 16) {
    float a = b1[tid];
    #pragma unroll
    for (int j=0;j<4;++j) a += st[j]*w1[j*16+tid];
    h1[tid] = fmaxf(a, 0.f);
  }
  __syncthreads();
  if (tid < 16) {
    float a = b2[tid];
    #pragma unroll
    for (int j=0;j<16;++j) a += h1[j]*w2[j*16+tid];
    h2[tid] = fmaxf(a, 0.f);
  }
  __syncthreads();
  int t = timesteps[b];
  const float* gr = gpe + (size_t)t*Dm;
  const float* pr = pos_emb + (size_t)s*Dm;
  float* xr = x + (size_t)bs*Dm;
  for (int o = tid; o < Dm; o += 256) {
    float a = b3[o];
    #pragma unroll
    for (int j=0;j<16;++j) a += h2[j]*w3[j*Dm+o];
    xr[o] = tanhf(a) + gr[o] + pr[o];
  }
}

// ---------------- layernorm, one block per token (row of 1024) ----------------
__global__ __launch_bounds__(256) void ln_kernel(
    const float* __restrict__ in, const float* __restrict__ g,
    const float* __restrict__ bb, float* __restrict__ out)
{
  int row = blockIdx.x, tid = threadIdx.x;
  const float* xr = in + (size_t)row*Dm;
  float vals[4];
  float s = 0.f;
  #pragma unroll
  for (int i=0;i<4;++i) { vals[i] = xr[tid + i*256]; s += vals[i]; }
  __shared__ float red[8];
  float v = s;
  #pragma unroll
  for (int off=32; off>0; off>>=1) v += __shfl_down(v, off, 64);
  if ((tid & 63) == 0) red[tid>>6] = v;
  __syncthreads();
  float mu = (red[0]+red[1]+red[2]+red[3]) * (1.f/Dm);
  float vs = 0.f;
  #pragma unroll
  for (int i=0;i<4;++i) { float d = vals[i]-mu; vs += d*d; }
  v = vs;
  #pragma unroll
  for (int off=32; off>0; off>>=1) v += __shfl_down(v, off, 64);
  if ((tid & 63) == 0) red[4+(tid>>6)] = v;
  __syncthreads();
  float var = (red[4]+red[5]+red[6]+red[7]) * (1.f/Dm);
  float inv = rsqrtf(var + 1e-5f);
  float* orow = out + (size_t)row*Dm;
  #pragma unroll
  for (int i=0;i<4;++i) {
    int c = tid + i*256;
    orow[c] = (vals[i]-mu)*inv*g[c] + bb[c];
  }
}

// ---------------- bf16x3 split helpers ----------------
// x = hi + lo + O(2^-17 |x|); hi = truncate-to-bf16, lo = RNE-bf16(x - hi)
__device__ __forceinline__ void split2(float x, unsigned short &hi, unsigned short &lo)
{
  unsigned u = __float_as_uint(x);
  hi = (unsigned short)(u >> 16);
  float r = x - __uint_as_float(u & 0xffff0000u);
  unsigned v = __float_as_uint(r);
  v += 0x7fffu + ((v >> 16) & 1u);
  lo = (unsigned short)(v >> 16);
}

// ---------------- bf16x3 MFMA GEMM: C = epi(A[M,K] @ W[K,N]) ----------------
// 128x128 tile, BK=32, 4 waves of 64x64, 16x16x32 bf16 MFMA, 3 products/frag.
// EPI: 0 none, 1 +bias, 2 +bias+resid, 3 +bias+exact GELU
template<int EPI>
__global__ __launch_bounds__(256, 2) void gemm_mfma(
    const float* __restrict__ A, const float* __restrict__ W,
    const float* __restrict__ bias, const float* __restrict__ resid,
    float* __restrict__ C, int M, int N, int K)
{
  // padded k-stride 40 (80B = 20 words): 8 consecutive rows cover all 32 banks
  __shared__ unsigned short Ahi[128][40];
  __shared__ unsigned short Alo[128][40];
  __shared__ unsigned short Bhi[128][40];
  __shared__ unsigned short Blo[128][40];

  const int tid = threadIdx.x;

  // --- chunked bijective block swizzle: one 16-wide N-chunk x all M-blocks
  //     (~512 blocks) co-resident -> W panel fetched ~once from HBM
  int bx, by;
  {
    const int nx = (int)gridDim.x, ny = (int)gridDim.y;
    const int lin = (int)blockIdx.y * nx + (int)blockIdx.x;
    const int Cx = 16;
    const int full = nx / Cx;
    const int rem = nx - full * Cx;
    const int body = full * Cx * ny;
    if (lin < body) {
      const int g = lin / (Cx * ny);
      const int r = lin - g * (Cx * ny);
      bx = g * Cx + (r & (Cx - 1));
      by = r >> 4;
    } else {
      const int r = lin - body;
      bx = full * Cx + (r % rem);
      by = r / rem;
    }
  }
  const int m0 = by * 128, n0 = bx * 128;

  // --- staging maps ---
  // A: thread -> (row, 8 consecutive k), 2 row-passes; coalesced 128B/row
  const int a_r = tid >> 2;            // 0..63 (+64 on pass 1)
  const int a_k = (tid & 3) * 8;       // 0,8,16,24
  // B: thread -> (one n, 16 consecutive k); lanes n-contiguous -> coalesced
  const int b_n = tid & 127;
  const int b_k = (tid >> 7) * 16;     // 0 or 16

  const float* Abase = A + (size_t)(m0 + a_r) * K + a_k;
  const float* Wbase = W + (size_t)b_k * N + n0 + b_n;

  // --- wave / fragment map: 4 waves as 2x2 of 64x64 ---
  const int lane = tid & 63;
  const int wid  = tid >> 6;
  const int wr = (wid >> 1) * 64, wc = (wid & 1) * 64;
  const int fr = lane & 15;            // frag row (A) / col (B)
  const int fk = (lane >> 4) * 8;      // k-group

  f32x4 acc[4][4] = {};

  float4 a_reg[2][2];
  float  b_reg[16];

  // prologue: load K-tile 0 into regs
  #pragma unroll
  for (int p = 0; p < 2; ++p) {
    a_reg[p][0] = *(const float4*)(Abase + (size_t)(p*64)*K);
    a_reg[p][1] = *(const float4*)(Abase + (size_t)(p*64)*K + 4);
  }
  #pragma unroll
  for (int j = 0; j < 16; ++j)
    b_reg[j] = Wbase[(size_t)j * N];

  const int nk = K >> 5;
  for (int kt = 0; kt < nk; ++kt) {
    __syncthreads();   // previous compute done reading LDS
    // --- split + store current regs to LDS ---
    #pragma unroll
    for (int p = 0; p < 2; ++p) {
      float vv[8] = {a_reg[p][0].x, a_reg[p][0].y, a_reg[p][0].z, a_reg[p][0].w,
                     a_reg[p][1].x, a_reg[p][1].y, a_reg[p][1].z, a_reg[p][1].w};
      ushort8v hv, lv;
      #pragma unroll
      for (int j = 0; j < 8; ++j) { unsigned short h, l; split2(vv[j], h, l); hv[j] = h; lv[j] = l; }
      *(ushort8v*)&Ahi[a_r + p*64][a_k] = hv;
      *(ushort8v*)&Alo[a_r + p*64][a_k] = lv;
    }
    #pragma unroll
    for (int h2 = 0; h2 < 2; ++h2) {
      ushort8v hv, lv;
      #pragma unroll
      for (int j = 0; j < 8; ++j) { unsigned short h, l; split2(b_reg[h2*8+j], h, l); hv[j] = h; lv[j] = l; }
      *(ushort8v*)&Bhi[b_n][b_k + h2*8] = hv;
      *(ushort8v*)&Blo[b_n][b_k + h2*8] = lv;
    }
    __syncthreads();   // tile visible
    // --- prefetch next K-tile into regs (hidden under MFMA phase) ---
    if (kt + 1 < nk) {
      const float* An = Abase + (kt + 1) * 32;
      #pragma unroll
      for (int p = 0; p < 2; ++p) {
        a_reg[p][0] = *(const float4*)(An + (size_t)(p*64)*K);
        a_reg[p][1] = *(const float4*)(An + (size_t)(p*64)*K + 4);
      }
      const float* Wn = Wbase + (size_t)(kt + 1) * 32 * N;
      #pragma unroll
      for (int j = 0; j < 16; ++j) b_reg[j] = Wn[(size_t)j * N];
    }
    // --- fragments + 48 MFMAs ---
    short8 ah[4], al[4], bh[4], bl[4];
    #pragma unroll
    for (int i = 0; i < 4; ++i) {
      ah[i] = *(const short8*)&Ahi[wr + i*16 + fr][fk];
      al[i] = *(const short8*)&Alo[wr + i*16 + fr][fk];
      bh[i] = *(const short8*)&Bhi[wc + i*16 + fr][fk];
      bl[i] = *(const short8*)&Blo[wc + i*16 + fr][fk];
    }
    #pragma unroll
    for (int i = 0; i < 4; ++i)
      #pragma unroll
      for (int j = 0; j < 4; ++j) {
        acc[i][j] = __builtin_amdgcn_mfma_f32_16x16x32_bf16(ah[i], bh[j], acc[i][j], 0, 0, 0);
        acc[i][j] = __builtin_amdgcn_mfma_f32_16x16x32_bf16(al[i], bh[j], acc[i][j], 0, 0, 0);
        acc[i][j] = __builtin_amdgcn_mfma_f32_16x16x32_bf16(ah[i], bl[j], acc[i][j], 0, 0, 0);
      }
  }

  // --- epilogue: C/D map col=lane&15, row=(lane>>4)*4+reg ---
  const int r0 = (lane >> 4) * 4;
  #pragma unroll
  for (int i = 0; i < 4; ++i) {
    #pragma unroll
    for (int j = 0; j < 4; ++j) {
      const int col = n0 + wc + j*16 + fr;
      #pragma unroll
      for (int r = 0; r < 4; ++r) {
        const int row = m0 + wr + i*16 + r0 + r;
        float vv = acc[i][j][r];
        if (EPI >= 1) vv += bias[col];
        if (EPI == 2) vv += resid[(size_t)row * N + col];
        if (EPI == 3) vv = 0.5f*vv*(1.f + erff(vv*0.70710678118654752f));
        C[(size_t)row * N + col] = vv;
      }
    }
  }
}

// ---------------- flash attention, 64x64 tiles, one block per (q-tile, b, h) ----------------
__global__ __launch_bounds__(256) void attn_kernel(
    const float* __restrict__ q, const float* __restrict__ k,
    const float* __restrict__ v, float* __restrict__ y)
{
  int qi = blockIdx.x;        // S/64 q-tiles
  int bh = blockIdx.y;        // B*H
  int b = bh >> 4, h = bh & 15;
  int tid = threadIdx.x;
  __shared__ float Qs[64][64], Ks[64][64], Vs[64][64], Ps[64][64];
  __shared__ float pmax[64][4], psum[64][4];
  __shared__ float mrow[64], lrow[64];
  const size_t base = ((size_t)b*Sseq)*Dm + (size_t)h*DHd;
  int s0 = qi*64;
  int lr = tid>>4, lc = (tid&15)<<2;
  #pragma unroll
  for (int it=0; it<4; ++it) {
    int r = lr + it*16;
    *(float4*)&Qs[r][lc] = *(const float4*)&q[base + (size_t)(s0+r)*Dm + lc];
  }
  if (tid < 64) { mrow[tid] = -INFINITY; lrow[tid] = 0.f; }
  int orow = tid>>2, oc0 = (tid&3)<<4;
  float O[16];
  #pragma unroll
  for (int c=0;c<16;++c) O[c]=0.f;
  const float scale = 0.125f;  // 1/sqrt(64)
  __syncthreads();
  for (int kj=0; kj<=qi; ++kj) {
    int t0g = kj*64;
    float mold = mrow[orow], lold = lrow[orow];
    #pragma unroll
    for (int it=0; it<4; ++it) {
      int r = lr + it*16;
      *(float4*)&Ks[r][lc] = *(const float4*)&k[base + (size_t)(t0g+r)*Dm + lc];
      *(float4*)&Vs[r][lc] = *(const float4*)&v[base + (size_t)(t0g+r)*Dm + lc];
    }
    __syncthreads();
    float sc[16];
    #pragma unroll
    for (int j=0;j<16;++j) sc[j]=0.f;
    for (int kk=0; kk<64; kk+=4) {
      float4 qv = *(const float4*)&Qs[orow][kk];
      #pragma unroll
      for (int j=0;j<16;++j) {
        float4 kv = *(const float4*)&Ks[oc0+j][kk];
        sc[j] += qv.x*kv.x + qv.y*kv.y + qv.z*kv.z + qv.w*kv.w;
      }
    }
    float tmax = -INFINITY;
    #pragma unroll
    for (int j=0;j<16;++j) {
      float val = sc[j]*scale;
      if (kj==qi && (t0g+oc0+j) > (s0+orow)) val = -INFINITY;
      sc[j]=val;
      tmax = fmaxf(tmax, val);
    }
    pmax[orow][tid&3] = tmax;
    __syncthreads();
    float mnew = fmaxf(mold, fmaxf(fmaxf(pmax[orow][0],pmax[orow][1]),
                                   fmaxf(pmax[orow][2],pmax[orow][3])));
    float alpha = expf(mold - mnew);
    float lsum = 0.f;
    #pragma unroll
    for (int j=0;j<16;++j) {
      float p = expf(sc[j]-mnew);
      Ps[orow][oc0+j] = p;
      lsum += p;
    }
    psum[orow][tid&3] = lsum;
    __syncthreads();
    float lnew = lold*alpha + psum[orow][0]+psum[orow][1]+psum[orow][2]+psum[orow][3];
    if ((tid&3)==0) { mrow[orow]=mnew; lrow[orow]=lnew; }
    #pragma unroll
    for (int c=0;c<16;++c) O[c] *= alpha;
    for (int t=0;t<64;++t) {
      float p = Ps[orow][t];
      #pragma unroll
      for (int c=0;c<16;c+=4) {
        float4 vv = *(const float4*)&Vs[t][oc0+c];
        O[c+0] = fmaf(p, vv.x, O[c+0]);
        O[c+1] = fmaf(p, vv.y, O[c+1]);
        O[c+2] = fmaf(p, vv.z, O[c+2]);
        O[c+3] = fmaf(p, vv.w, O[c+3]);
      }
    }
    __syncthreads();
  }
  float linv = 1.f / lrow[orow];
  #pragma unroll
  for (int c=0;c<16;++c) {
    y[base + (size_t)(s0+orow)*Dm + oc0 + c] = O[c]*linv;
  }
}

extern "C" void kernel_launch(void* const* d_in, const int* in_sizes, int n_in,
                              void* d_out, int out_size, void* d_ws, size_t ws_size,
                              hipStream_t stream)
{
  const float* states   = (const float*)d_in[0];
  const int*   timesteps= (const int*)d_in[1];
  const float* se_w1=(const float*)d_in[2];  const float* se_b1=(const float*)d_in[3];
  const float* se_w2=(const float*)d_in[4];  const float* se_b2=(const float*)d_in[5];
  const float* se_w3=(const float*)d_in[6];  const float* se_b3=(const float*)d_in[7];
  const float* pos_emb=(const float*)d_in[8];const float* gpe=(const float*)d_in[9];
  const float* ln1_g=(const float*)d_in[10]; const float* ln1_b=(const float*)d_in[11];
  const float* Wq=(const float*)d_in[12];    const float* Wk=(const float*)d_in[13];
  const float* Wv=(const float*)d_in[14];    const float* Wp=(const float*)d_in[15];
  const float* bp=(const float*)d_in[16];
  const float* ln2_g=(const float*)d_in[17]; const float* ln2_b=(const float*)d_in[18];
  const float* W1=(const float*)d_in[19];    const float* b1=(const float*)d_in[20];
  const float* W2=(const float*)d_in[21];    const float* b2=(const float*)d_in[22];
  const float* lnf_g=(const float*)d_in[23]; const float* lnf_b=(const float*)d_in[24];
  const float* head_w=(const float*)d_in[25];
  float* out = (float*)d_out;

  const size_t TD = (size_t)NT*Dm; // 4M floats per activation buffer
  float* x  = (float*)d_ws;  // 16 MB each
  float* hn = x + TD;
  float* q  = hn + TD;
  float* k  = q + TD;
  float* v  = k + TD;
  float* y  = v + TD;
  float* hmlp = q;           // alias: q..y region = 4*TD = NT*Dff floats exactly

  encoder_kernel<<<NT, 256, 0, stream>>>(states, timesteps, se_w1, se_b1, se_w2,
                                         se_b2, se_w3, se_b3, pos_emb, gpe, x);

  dim3 gDD(Dm/128, NT/128);
  for (int l=0; l<Ll; ++l) {
    const float* wq = Wq + (size_t)l*Dm*Dm;
    const float* wk = Wk + (size_t)l*Dm*Dm;
    const float* wv = Wv + (size_t)l*Dm*Dm;
    const float* wp = Wp + (size_t)l*Dm*Dm;
    const float* w1 = W1 + (size_t)l*Dm*Dff;
    const float* w2 = W2 + (size_t)l*Dff*Dm;

    ln_kernel<<<NT,256,0,stream>>>(x, ln1_g + l*Dm, ln1_b + l*Dm, hn);
    gemm_mfma<0><<<gDD,256,0,stream>>>(hn, wq, nullptr, nullptr, q, NT, Dm, Dm);
    gemm_mfma<0><<<gDD,256,0,stream>>>(hn, wk, nullptr, nullptr, k, NT, Dm, Dm);
    gemm_mfma<0><<<gDD,256,0,stream>>>(hn, wv, nullptr, nullptr, v, NT, Dm, Dm);
    attn_kernel<<<dim3(Sseq/64, Bsz*Hh),256,0,stream>>>(q, k, v, y);
    gemm_mfma<2><<<gDD,256,0,stream>>>(y, wp, bp + l*Dm, x, x, NT, Dm, Dm);
    ln_kernel<<<NT,256,0,stream>>>(x, ln2_g + l*Dm, ln2_b + l*Dm, hn);
    gemm_mfma<3><<<dim3(Dff/128, NT/128),256,0,stream>>>(hn, w1, b1 + l*Dff, nullptr,
                                                         hmlp, NT, Dff, Dm);
    gemm_mfma<2><<<gDD,256,0,stream>>>(hmlp, w2, b2 + l*Dm, x, x, NT, Dm, Dff);
  }
  ln_kernel<<<NT,256,0,stream>>>(x, lnf_g, lnf_b, hn);
  gemm_mfma<0><<<dim3(Vv/128, NT/128),256,0,stream>>>(hn, head_w, nullptr, nullptr,
                                                      out, NT, Vv, Dm);
}